// Round 4
// baseline (380.937 us; speedup 1.0000x reference)
//
#include <hip/hip_runtime.h>
#include <hip/hip_cooperative_groups.h>
#include <math.h>

namespace cg = cooperative_groups;

#define H 2048
#define V 50257
#define ML 25
#define NBLK 512
#define NWAVE (NBLK * 4)            // 2048 waves
#define GH_WAVES ((NBLK - 1) * 4)   // worker waves in phase A

// ---- mega ws layout (floats) ----
#define WS_EMB 16                   // embedded [H]
#define WS_ATT (WS_EMB + H)         // attn_applied [H] (contiguous after EMB -> cat[2H])
#define WS_X   (WS_EMB + 2 * H)     // relu(combine) [H]
#define WS_GH  (WS_X + H)           // gh = W_hh@h + b_hh [3H]
#define WS_PM  (WS_GH + 3 * H)      // per-wave running max [NWAVE]
#define WS_PS  (WS_PM + NWAVE)      // per-wave running sumexp [NWAVE]

// ---- fallback ws layout (floats) ----
#define FB_M   0
#define FB_L   1
#define FB_EMB 16
#define FB_ATT (FB_EMB + H)
#define FB_X   (FB_ATT + H)
#define FB_PM  (FB_X + H)
#define FB_PS  (FB_PM + 6400)
#define NB4 ((V + 7) / 8)

typedef float f4v __attribute__((ext_vector_type(4)));

__device__ __forceinline__ f4v ntload(const f4v* p) { return __builtin_nontemporal_load(p); }
__device__ __forceinline__ float dot4(f4v a, f4v b) {
    return a[0] * b[0] + a[1] * b[1] + a[2] * b[2] + a[3] * b[3];
}
__device__ __forceinline__ float wave_sum(float x) {
    #pragma unroll
    for (int off = 32; off; off >>= 1) x += __shfl_xor(x, off);
    return x;
}

// ==================== cooperative mega-kernel ====================
__global__ __launch_bounds__(256, 2)
void mega(const int* __restrict__ tok_p, const float* __restrict__ hidden,
          const float* __restrict__ enc_outs, const float* __restrict__ emb,
          const float* __restrict__ W_attn, const float* __restrict__ b_attn,
          const float* __restrict__ W_comb, const float* __restrict__ b_comb,
          const float* __restrict__ W_ih, const float* __restrict__ W_hh,
          const float* __restrict__ b_ih, const float* __restrict__ b_hh,
          const float* __restrict__ W_out, const float* __restrict__ b_out,
          float* __restrict__ ws, float* __restrict__ logits,
          float* __restrict__ h_out, float* __restrict__ attnw)
{
    cg::grid_group grid = cg::this_grid();
    __shared__ __align__(16) float s_cat[2 * H];
    __shared__ float s_aw[ML];
    __shared__ float s_red[8];

    const int tid = threadIdx.x;
    const int bid = blockIdx.x;
    const int wv = tid >> 6, lane = tid & 63;
    const int gw = bid * 4 + wv;

    // ---------- Phase A: block 0 = attention; blocks 1.. = gh = W_hh@h + b_hh ----------
    if (bid == 0) {
        const int tok = tok_p[0];   // int64 input, low word
        const float* erow = emb + (size_t)tok * H;
        for (int h = tid; h < H; h += 256) {
            float e = erow[h];
            s_cat[h] = e; ws[WS_EMB + h] = e;
            s_cat[H + h] = hidden[h];
        }
        __syncthreads();
        for (int l = wv; l < ML; l += 4) {
            const float* wrow = W_attn + (size_t)l * (2 * H);
            float acc = 0.f;
            for (int j = lane; j < 2 * H; j += 64) acc += wrow[j] * s_cat[j];
            acc = wave_sum(acc);
            if (lane == 0) s_aw[l] = acc + b_attn[l];
        }
        __syncthreads();
        if (tid == 0) {
            float m = s_aw[0];
            for (int l = 1; l < ML; ++l) m = fmaxf(m, s_aw[l]);
            float s = 0.f;
            for (int l = 0; l < ML; ++l) { float e = expf(s_aw[l] - m); s_aw[l] = e; s += e; }
            float inv = 1.f / s;
            for (int l = 0; l < ML; ++l) { float w = s_aw[l] * inv; s_aw[l] = w; attnw[l] = w; }
        }
        __syncthreads();
        for (int h = tid; h < H; h += 256) {
            float acc = 0.f;
            #pragma unroll
            for (int l = 0; l < ML; ++l) acc += s_aw[l] * enc_outs[(size_t)l * H + h];
            ws[WS_ATT + h] = acc;
        }
    } else {
        const int gw2 = (bid - 1) * 4 + wv;
        const f4v* h4 = reinterpret_cast<const f4v*>(hidden);
        for (int r = gw2; r < 3 * H; r += GH_WAVES) {
            const f4v* w4 = reinterpret_cast<const f4v*>(W_hh + (size_t)r * H);
            float acc = 0.f;
            #pragma unroll
            for (int t = 0; t < 8; ++t) {
                int idx = t * 64 + lane;
                acc += dot4(ntload(&w4[idx]), h4[idx]);
            }
            acc = wave_sum(acc);
            if (lane == 0) ws[WS_GH + r] = acc + b_hh[r];
        }
    }
    grid.sync();

    // ---------- Phase B: x = relu(W_comb @ cat + b_comb) ----------
    if (gw < H) {
        const int k = gw;
        const f4v* w4 = reinterpret_cast<const f4v*>(W_comb + (size_t)k * (2 * H));
        const f4v* c4 = reinterpret_cast<const f4v*>(ws + WS_EMB);
        float acc = 0.f;
        #pragma unroll
        for (int t = 0; t < 16; ++t) {
            int idx = t * 64 + lane;
            acc += dot4(ntload(&w4[idx]), c4[idx]);
        }
        acc = wave_sum(acc);
        if (lane == 0) ws[WS_X + k] = fmaxf(acc + b_comb[k], 0.f);
    }
    grid.sync();

    // ---------- Phase C: gi = W_ih @ x; gates; h_new ----------
    if (gw < H) {
        const int k = gw;
        const f4v* x4 = reinterpret_cast<const f4v*>(ws + WS_X);
        const f4v* wr = reinterpret_cast<const f4v*>(W_ih + (size_t)k * H);
        const f4v* wz = reinterpret_cast<const f4v*>(W_ih + (size_t)(k + H) * H);
        const f4v* wn = reinterpret_cast<const f4v*>(W_ih + (size_t)(k + 2 * H) * H);
        float ar = 0.f, az = 0.f, an = 0.f;
        #pragma unroll
        for (int t = 0; t < 8; ++t) {
            int idx = t * 64 + lane;
            f4v xv = x4[idx];
            ar += dot4(ntload(&wr[idx]), xv);
            az += dot4(ntload(&wz[idx]), xv);
            an += dot4(ntload(&wn[idx]), xv);
        }
        ar = wave_sum(ar); az = wave_sum(az); an = wave_sum(an);
        float ir = ar + b_ih[k], iz = az + b_ih[k + H], inn = an + b_ih[k + 2 * H];
        float hr = ws[WS_GH + k], hz = ws[WS_GH + k + H], hn = ws[WS_GH + k + 2 * H];
        float r = 1.f / (1.f + expf(-(ir + hr)));
        float z = 1.f / (1.f + expf(-(iz + hz)));
        float n = tanhf(inn + r * hn);
        if (lane == 0) h_out[k] = (1.f - z) * n + z * hidden[k];
    }
    grid.sync();

    // ---------- Phase D: logits GEMV + per-wave online logsumexp ----------
    {
        const f4v* h4 = reinterpret_cast<const f4v*>(h_out);
        f4v hv[8];
        #pragma unroll
        for (int t = 0; t < 8; ++t) hv[t] = h4[t * 64 + lane];
        float m_w = -INFINITY, s_w = 0.f;
        for (int row = gw; row < V; row += NWAVE) {
            const f4v* w4 = reinterpret_cast<const f4v*>(W_out + (size_t)row * H);
            float acc = 0.f;
            #pragma unroll
            for (int t = 0; t < 8; ++t) {
                int idx = t * 64 + lane;
                acc += dot4(ntload(&w4[idx]), hv[t]);
            }
            acc = wave_sum(acc);
            float l = acc + b_out[row];
            if (lane == 0) logits[row] = l;
            if (l > m_w) { s_w = s_w * expf(m_w - l) + 1.f; m_w = l; }
            else         { s_w += expf(l - m_w); }
        }
        if (lane == 0) { ws[WS_PM + gw] = m_w; ws[WS_PS + gw] = s_w; }
    }
    grid.sync();

    // ---------- Phase F: every block reduces partials, applies log-softmax stripe ----------
    {
        float m = -INFINITY;
        for (int i = tid; i < NWAVE; i += 256) m = fmaxf(m, ws[WS_PM + i]);
        #pragma unroll
        for (int off = 32; off; off >>= 1) m = fmaxf(m, __shfl_xor(m, off));
        if (lane == 0) s_red[wv] = m;
        __syncthreads();
        if (tid == 0) {
            float mm = fmaxf(fmaxf(s_red[0], s_red[1]), fmaxf(s_red[2], s_red[3]));
            s_red[0] = mm;
        }
        __syncthreads();
        const float M = s_red[0];
        float s = 0.f;
        for (int i = tid; i < NWAVE; i += 256) s += ws[WS_PS + i] * expf(ws[WS_PM + i] - M);
        s = wave_sum(s);
        if (lane == 0) s_red[4 + wv] = s;
        __syncthreads();
        if (tid == 0) {
            float ss = s_red[4] + s_red[5] + s_red[6] + s_red[7];
            s_red[1] = M + logf(ss);
        }
        __syncthreads();
        const float ML_sum = s_red[1];
        for (int v = bid * 256 + tid; v < V; v += NBLK * 256) logits[v] -= ML_sum;
    }
}

// ==================== fallback chain (proven round-2 kernels) ====================
__global__ __launch_bounds__(1024)
void k1_attn(const int* tok_p, const float* hidden, const float* enc_outs,
             const float* emb, const float* W_attn, const float* b_attn,
             float* ws, float* out_attnw)
{
    __shared__ __align__(16) float s_cat[2 * H];
    __shared__ float s_w[ML];
    const int tid = threadIdx.x;
    const int tok = tok_p[0];
    const float* erow = emb + (size_t)tok * H;
    for (int h = tid; h < H; h += 1024) {
        float e = erow[h];
        s_cat[h] = e;
        ws[FB_EMB + h] = e;
        s_cat[H + h] = hidden[h];
    }
    __syncthreads();
    const int wave = tid >> 6, lane = tid & 63;
    for (int l = wave; l < ML; l += 16) {
        const float* wrow = W_attn + (size_t)l * (2 * H);
        float acc = 0.f;
        for (int j = lane; j < 2 * H; j += 64) acc += wrow[j] * s_cat[j];
        acc = wave_sum(acc);
        if (lane == 0) s_w[l] = acc + b_attn[l];
    }
    __syncthreads();
    if (tid == 0) {
        float m = s_w[0];
        for (int l = 1; l < ML; ++l) m = fmaxf(m, s_w[l]);
        float s = 0.f;
        for (int l = 0; l < ML; ++l) { float e = expf(s_w[l] - m); s_w[l] = e; s += e; }
        float inv = 1.f / s;
        for (int l = 0; l < ML; ++l) { s_w[l] *= inv; out_attnw[l] = s_w[l]; }
    }
    __syncthreads();
    for (int h = tid; h < H; h += 1024) {
        float acc = 0.f;
        #pragma unroll
        for (int l = 0; l < ML; ++l) acc += s_w[l] * enc_outs[(size_t)l * H + h];
        ws[FB_ATT + h] = acc;
    }
}

__global__ __launch_bounds__(256)
void k2_combine(const float* __restrict__ W_comb, const float* __restrict__ b_comb,
                float* __restrict__ ws)
{
    const int tid = threadIdx.x;
    const int wave = tid >> 6, lane = tid & 63;
    const int k = blockIdx.x * 4 + wave;
    const f4v* w4 = reinterpret_cast<const f4v*>(W_comb + (size_t)k * (2 * H));
    const f4v* c4 = reinterpret_cast<const f4v*>(ws + FB_EMB);
    float acc = 0.f;
    #pragma unroll
    for (int t = 0; t < 16; ++t) {
        int idx = t * 64 + lane;
        acc += dot4(ntload(&w4[idx]), c4[idx]);
    }
    acc = wave_sum(acc);
    if (lane == 0) ws[FB_X + k] = fmaxf(acc + b_comb[k], 0.f);
}

__global__ __launch_bounds__(256)
void k3_gru(const float* __restrict__ W_ih, const float* __restrict__ W_hh,
            const float* __restrict__ b_ih, const float* __restrict__ b_hh,
            const float* __restrict__ hidden, const float* __restrict__ ws,
            float* __restrict__ h_out)
{
    const int tid = threadIdx.x;
    const int wave = tid >> 6, lane = tid & 63;
    const int k = blockIdx.x * 4 + wave;
    const f4v* x4 = reinterpret_cast<const f4v*>(ws + FB_X);
    const f4v* h4 = reinterpret_cast<const f4v*>(hidden);
    const f4v* wi_r = reinterpret_cast<const f4v*>(W_ih + (size_t)k * H);
    const f4v* wi_z = reinterpret_cast<const f4v*>(W_ih + (size_t)(k + H) * H);
    const f4v* wi_n = reinterpret_cast<const f4v*>(W_ih + (size_t)(k + 2 * H) * H);
    const f4v* wh_r = reinterpret_cast<const f4v*>(W_hh + (size_t)k * H);
    const f4v* wh_z = reinterpret_cast<const f4v*>(W_hh + (size_t)(k + H) * H);
    const f4v* wh_n = reinterpret_cast<const f4v*>(W_hh + (size_t)(k + 2 * H) * H);
    float a_r = 0, a_z = 0, a_n = 0, g_r = 0, g_z = 0, g_n = 0;
    #pragma unroll
    for (int t = 0; t < 8; ++t) {
        int idx = t * 64 + lane;
        f4v xv = x4[idx], hv = h4[idx];
        a_r += dot4(ntload(&wi_r[idx]), xv);
        a_z += dot4(ntload(&wi_z[idx]), xv);
        a_n += dot4(ntload(&wi_n[idx]), xv);
        g_r += dot4(ntload(&wh_r[idx]), hv);
        g_z += dot4(ntload(&wh_z[idx]), hv);
        g_n += dot4(ntload(&wh_n[idx]), hv);
    }
    #pragma unroll
    for (int off = 32; off; off >>= 1) {
        a_r += __shfl_xor(a_r, off); a_z += __shfl_xor(a_z, off); a_n += __shfl_xor(a_n, off);
        g_r += __shfl_xor(g_r, off); g_z += __shfl_xor(g_z, off); g_n += __shfl_xor(g_n, off);
    }
    if (lane == 0) {
        float ir = a_r + b_ih[k], iz = a_z + b_ih[k + H], inn = a_n + b_ih[k + 2 * H];
        float hr = g_r + b_hh[k], hz = g_z + b_hh[k + H], hn = g_n + b_hh[k + 2 * H];
        float r = 1.f / (1.f + expf(-(ir + hr)));
        float z = 1.f / (1.f + expf(-(iz + hz)));
        float n = tanhf(inn + r * hn);
        h_out[k] = (1.f - z) * n + z * hidden[k];
    }
}

__global__ __launch_bounds__(256)
void k4_logits(const float* __restrict__ W_out, const float* __restrict__ b_out,
               const float* __restrict__ h_new, float* __restrict__ logits,
               float* __restrict__ ws)
{
    __shared__ float s_val[8];
    const int tid = threadIdx.x;
    if (tid < 8) s_val[tid] = -INFINITY;
    const int wave = tid >> 6, lane = tid & 63;
    const int row0 = blockIdx.x * 8 + wave * 2;
    const int row1 = row0 + 1;
    const bool v0 = row0 < V, v1 = row1 < V;
    const size_t r0 = v0 ? (size_t)row0 : 0;
    const size_t r1 = v1 ? (size_t)row1 : 0;
    const f4v* h4 = reinterpret_cast<const f4v*>(h_new);
    f4v hv[8];
    #pragma unroll
    for (int t = 0; t < 8; ++t) hv[t] = h4[t * 64 + lane];
    const f4v* w0 = reinterpret_cast<const f4v*>(W_out + r0 * H);
    const f4v* w1 = reinterpret_cast<const f4v*>(W_out + r1 * H);
    float a0 = 0.f, a1 = 0.f;
    #pragma unroll
    for (int t = 0; t < 8; ++t) {
        int idx = t * 64 + lane;
        a0 += dot4(ntload(&w0[idx]), hv[t]);
        a1 += dot4(ntload(&w1[idx]), hv[t]);
    }
    #pragma unroll
    for (int off = 32; off; off >>= 1) { a0 += __shfl_xor(a0, off); a1 += __shfl_xor(a1, off); }
    __syncthreads();
    if (lane == 0) {
        if (v0) { float l0 = a0 + b_out[row0]; logits[row0] = l0; s_val[wave * 2]     = l0; }
        if (v1) { float l1 = a1 + b_out[row1]; logits[row1] = l1; s_val[wave * 2 + 1] = l1; }
    }
    __syncthreads();
    if (tid == 0) {
        float m = s_val[0];
        #pragma unroll
        for (int i = 1; i < 8; ++i) m = fmaxf(m, s_val[i]);
        float s = 0.f;
        #pragma unroll
        for (int i = 0; i < 8; ++i) s += expf(s_val[i] - m);
        ws[FB_PM + blockIdx.x] = m;
        ws[FB_PS + blockIdx.x] = s;
    }
}

__global__ __launch_bounds__(1024)
void k5_combine(float* ws)
{
    __shared__ float s_red[16];
    const int tid = threadIdx.x;
    const int wave = tid >> 6, lane = tid & 63;
    const float* pm = ws + FB_PM;
    const float* ps = ws + FB_PS;
    float m = -INFINITY;
    for (int i = tid; i < NB4; i += 1024) m = fmaxf(m, pm[i]);
    #pragma unroll
    for (int off = 32; off; off >>= 1) m = fmaxf(m, __shfl_xor(m, off));
    if (lane == 0) s_red[wave] = m;
    __syncthreads();
    if (tid == 0) {
        float mm = s_red[0];
        for (int w = 1; w < 16; ++w) mm = fmaxf(mm, s_red[w]);
        s_red[0] = mm;
    }
    __syncthreads();
    m = s_red[0];
    __syncthreads();
    float s = 0.f;
    for (int i = tid; i < NB4; i += 1024) s += ps[i] * expf(pm[i] - m);
    s = wave_sum(s);
    if (lane == 0) s_red[wave] = s;
    __syncthreads();
    if (tid == 0) {
        float ss = 0.f;
        for (int w = 0; w < 16; ++w) ss += s_red[w];
        ws[FB_M] = m;
        ws[FB_L] = logf(ss);
    }
}

__global__ __launch_bounds__(256)
void k6_apply(float* logits, const float* ws)
{
    const int v = blockIdx.x * 256 + threadIdx.x;
    if (v < V) logits[v] = logits[v] - ws[FB_M] - ws[FB_L];
}

extern "C" void kernel_launch(void* const* d_in, const int* in_sizes, int n_in,
                              void* d_out, int out_size, void* d_ws, size_t ws_size,
                              hipStream_t stream)
{
    const int*   tok      = (const int*)d_in[0];
    const float* hidden   = (const float*)d_in[1];
    const float* enc_outs = (const float*)d_in[3];
    const float* emb      = (const float*)d_in[4];
    const float* W_attn   = (const float*)d_in[5];
    const float* b_attn   = (const float*)d_in[6];
    const float* W_comb   = (const float*)d_in[7];
    const float* b_comb   = (const float*)d_in[8];
    const float* W_ih     = (const float*)d_in[9];
    const float* W_hh     = (const float*)d_in[10];
    const float* b_ih     = (const float*)d_in[11];
    const float* b_hh     = (const float*)d_in[12];
    const float* W_out    = (const float*)d_in[13];
    const float* b_out    = (const float*)d_in[14];

    float* out    = (float*)d_out;
    float* ws     = (float*)d_ws;
    float* logits = out;
    float* h_out  = out + V;
    float* attnw  = out + V + H;

    void* args[] = {
        (void*)&tok, (void*)&hidden, (void*)&enc_outs, (void*)&emb,
        (void*)&W_attn, (void*)&b_attn, (void*)&W_comb, (void*)&b_comb,
        (void*)&W_ih, (void*)&W_hh, (void*)&b_ih, (void*)&b_hh,
        (void*)&W_out, (void*)&b_out,
        (void*)&ws, (void*)&logits, (void*)&h_out, (void*)&attnw
    };
    hipError_t err = hipLaunchCooperativeKernel((const void*)mega, dim3(NBLK), dim3(256),
                                                args, 0, stream);
    if (err != hipSuccess) {
        (void)hipGetLastError();   // clear sticky error, run proven fallback chain
        k1_attn   <<<1,            1024, 0, stream>>>(tok, hidden, enc_outs, emb, W_attn, b_attn, ws, attnw);
        k2_combine<<<H / 4,         256, 0, stream>>>(W_comb, b_comb, ws);
        k3_gru    <<<H / 4,         256, 0, stream>>>(W_ih, W_hh, b_ih, b_hh, hidden, ws, h_out);
        k4_logits <<<NB4,           256, 0, stream>>>(W_out, b_out, h_out, logits, ws);
        k5_combine<<<1,            1024, 0, stream>>>(ws);
        k6_apply  <<<(V + 255) / 256, 256, 0, stream>>>(logits, ws);
    }
}

// Round 5
// 105.040 us; speedup vs baseline: 3.6266x; 3.6266x over previous
//
#include <hip/hip_runtime.h>
#include <math.h>

#define H 2048
#define V 50257
#define ML 25

#define NBD ((V + 15) / 16)     // 3142 blocks in kD, 16 rows/block
#define NPART NBD

// ws layout (floats)
#define WS_EMB 16                // embedded [H]
#define WS_ATT (WS_EMB + H)      // attn_applied [H] (contiguous -> cat[2H])
#define WS_X   (WS_EMB + 2 * H)  // relu(combine) [H]
#define WS_GH  (WS_X + H)        // gh = W_hh@h + b_hh [3H]
#define WS_PM  (WS_GH + 3 * H)   // per-block max partials [NPART]
#define WS_PS  (WS_PM + 3200)    // per-block sumexp partials [NPART]

typedef float f4v __attribute__((ext_vector_type(4)));

__device__ __forceinline__ f4v ntload(const f4v* p) { return __builtin_nontemporal_load(p); }
__device__ __forceinline__ float dot4(f4v a, f4v b) {
    return a[0] * b[0] + a[1] * b[1] + a[2] * b[2] + a[3] * b[3];
}
__device__ __forceinline__ float wave_sum(float x) {
    #pragma unroll
    for (int off = 32; off; off >>= 1) x += __shfl_xor(x, off);
    return x;
}

// ============ kA: block 0 = embedding+attention; blocks 1..384 = gh = W_hh@h + b_hh ============
__global__ __launch_bounds__(1024)
void kA(const int* __restrict__ tok_p, const float* __restrict__ hidden,
        const float* __restrict__ enc_outs, const float* __restrict__ emb,
        const float* __restrict__ W_attn, const float* __restrict__ b_attn,
        const float* __restrict__ W_hh, const float* __restrict__ b_hh,
        float* __restrict__ ws, float* __restrict__ attnw)
{
    const int tid = threadIdx.x, bid = blockIdx.x;
    const int wv = tid >> 6, lane = tid & 63;

    if (bid == 0) {
        __shared__ __align__(16) float s_cat[2 * H];
        __shared__ float s_aw[ML];
        const int tok = tok_p[0];   // int64 input, low word (LE)
        const float* erow = emb + (size_t)tok * H;
        for (int h = tid; h < H; h += 1024) {
            float e = erow[h];
            s_cat[h] = e; ws[WS_EMB + h] = e;
            s_cat[H + h] = hidden[h];
        }
        __syncthreads();
        const f4v* c4 = reinterpret_cast<const f4v*>(s_cat);
        for (int l = wv; l < ML; l += 16) {
            const f4v* w4 = reinterpret_cast<const f4v*>(W_attn + (size_t)l * (2 * H));
            float acc = 0.f;
            #pragma unroll
            for (int t = 0; t < 16; ++t) {
                int idx = t * 64 + lane;
                acc += dot4(w4[idx], c4[idx]);
            }
            acc = wave_sum(acc);
            if (lane == 0) s_aw[l] = acc + b_attn[l];
        }
        __syncthreads();
        if (tid == 0) {
            float m = s_aw[0];
            for (int l = 1; l < ML; ++l) m = fmaxf(m, s_aw[l]);
            float s = 0.f;
            for (int l = 0; l < ML; ++l) { float e = expf(s_aw[l] - m); s_aw[l] = e; s += e; }
            float inv = 1.f / s;
            for (int l = 0; l < ML; ++l) { float w = s_aw[l] * inv; s_aw[l] = w; attnw[l] = w; }
        }
        __syncthreads();
        for (int h = tid; h < H; h += 1024) {
            float acc = 0.f;
            #pragma unroll
            for (int l = 0; l < ML; ++l) acc += s_aw[l] * enc_outs[(size_t)l * H + h];
            ws[WS_ATT + h] = acc;
        }
    } else {
        const int r = (bid - 1) * 16 + wv;   // 6144 rows over 384 blocks
        if (r < 3 * H) {
            const f4v* w4 = reinterpret_cast<const f4v*>(W_hh + (size_t)r * H);
            const f4v* h4 = reinterpret_cast<const f4v*>(hidden);
            float acc = 0.f;
            #pragma unroll
            for (int t = 0; t < 8; ++t) {
                int idx = t * 64 + lane;
                acc += dot4(ntload(&w4[idx]), h4[idx]);
            }
            acc = wave_sum(acc);
            if (lane == 0) ws[WS_GH + r] = acc + b_hh[r];
        }
    }
}

// ============ kB: x = relu(W_comb @ cat + b_comb) ============
__global__ __launch_bounds__(256)
void kB(const float* __restrict__ W_comb, const float* __restrict__ b_comb,
        float* __restrict__ ws)
{
    const int tid = threadIdx.x;
    const int wv = tid >> 6, lane = tid & 63;
    const int k = blockIdx.x * 4 + wv;
    const f4v* w4 = reinterpret_cast<const f4v*>(W_comb + (size_t)k * (2 * H));
    const f4v* c4 = reinterpret_cast<const f4v*>(ws + WS_EMB);
    float acc = 0.f;
    #pragma unroll
    for (int t = 0; t < 16; ++t) {
        int idx = t * 64 + lane;
        acc += dot4(ntload(&w4[idx]), c4[idx]);
    }
    acc = wave_sum(acc);
    if (lane == 0) ws[WS_X + k] = fmaxf(acc + b_comb[k], 0.f);
}

// ============ kC: gi = W_ih @ x; gates; h_new ============
__global__ __launch_bounds__(256)
void kC(const float* __restrict__ W_ih, const float* __restrict__ b_ih,
        const float* __restrict__ hidden, const float* __restrict__ ws,
        float* __restrict__ h_out)
{
    const int tid = threadIdx.x;
    const int wv = tid >> 6, lane = tid & 63;
    const int k = blockIdx.x * 4 + wv;
    const f4v* x4 = reinterpret_cast<const f4v*>(ws + WS_X);
    const f4v* wr = reinterpret_cast<const f4v*>(W_ih + (size_t)k * H);
    const f4v* wz = reinterpret_cast<const f4v*>(W_ih + (size_t)(k + H) * H);
    const f4v* wn = reinterpret_cast<const f4v*>(W_ih + (size_t)(k + 2 * H) * H);
    float ar = 0.f, az = 0.f, an = 0.f;
    #pragma unroll
    for (int t = 0; t < 8; ++t) {
        int idx = t * 64 + lane;
        f4v xv = x4[idx];
        ar += dot4(ntload(&wr[idx]), xv);
        az += dot4(ntload(&wz[idx]), xv);
        an += dot4(ntload(&wn[idx]), xv);
    }
    ar = wave_sum(ar); az = wave_sum(az); an = wave_sum(an);
    if (lane == 0) {
        float ir = ar + b_ih[k], iz = az + b_ih[k + H], inn = an + b_ih[k + 2 * H];
        float hr = ws[WS_GH + k], hz = ws[WS_GH + k + H], hn = ws[WS_GH + k + 2 * H];
        float r = 1.f / (1.f + expf(-(ir + hr)));
        float z = 1.f / (1.f + expf(-(iz + hz)));
        float n = tanhf(inn + r * hn);
        h_out[k] = (1.f - z) * n + z * hidden[k];
    }
}

// ============ kD: logits GEMV (4 rows/wave, 16 rows/block) + block partials ============
__global__ __launch_bounds__(256)
void kD(const float* __restrict__ W_out, const float* __restrict__ b_out,
        const float* __restrict__ h_new, float* __restrict__ logits,
        float* __restrict__ ws)
{
    __shared__ float s_m[4], s_s[4];
    const int tid = threadIdx.x;
    const int wv = tid >> 6, lane = tid & 63;
    const int rbase = blockIdx.x * 16 + wv * 4;

    const f4v* h4 = reinterpret_cast<const f4v*>(h_new);
    f4v hv[8];
    #pragma unroll
    for (int t = 0; t < 8; ++t) hv[t] = h4[t * 64 + lane];

    const int  r0 = rbase, r1 = rbase + 1, r2 = rbase + 2, r3 = rbase + 3;
    const bool v0 = r0 < V, v1 = r1 < V, v2 = r2 < V, v3 = r3 < V;
    const f4v* w0 = reinterpret_cast<const f4v*>(W_out + (size_t)(v0 ? r0 : 0) * H);
    const f4v* w1 = reinterpret_cast<const f4v*>(W_out + (size_t)(v1 ? r1 : 0) * H);
    const f4v* w2 = reinterpret_cast<const f4v*>(W_out + (size_t)(v2 ? r2 : 0) * H);
    const f4v* w3 = reinterpret_cast<const f4v*>(W_out + (size_t)(v3 ? r3 : 0) * H);

    float a0 = 0.f, a1 = 0.f, a2 = 0.f, a3 = 0.f;
    #pragma unroll
    for (int t = 0; t < 8; ++t) {
        int idx = t * 64 + lane;
        a0 += dot4(ntload(&w0[idx]), hv[t]);
        a1 += dot4(ntload(&w1[idx]), hv[t]);
        a2 += dot4(ntload(&w2[idx]), hv[t]);
        a3 += dot4(ntload(&w3[idx]), hv[t]);
    }
    #pragma unroll
    for (int off = 32; off; off >>= 1) {
        a0 += __shfl_xor(a0, off); a1 += __shfl_xor(a1, off);
        a2 += __shfl_xor(a2, off); a3 += __shfl_xor(a3, off);
    }
    const float l0 = v0 ? a0 + b_out[r0] : -INFINITY;
    const float l1 = v1 ? a1 + b_out[r1] : -INFINITY;
    const float l2 = v2 ? a2 + b_out[r2] : -INFINITY;
    const float l3 = v3 ? a3 + b_out[r3] : -INFINITY;
    if (lane == 0) {
        if (v0) logits[r0] = l0;
        if (v1) logits[r1] = l1;
        if (v2) logits[r2] = l2;
        if (v3) logits[r3] = l3;
        float m = fmaxf(fmaxf(l0, l1), fmaxf(l2, l3));
        float s = 0.f;
        if (m > -INFINITY)
            s = expf(l0 - m) + expf(l1 - m) + expf(l2 - m) + expf(l3 - m);
        s_m[wv] = m; s_s[wv] = s;
    }
    __syncthreads();
    if (tid == 0) {
        float M = fmaxf(fmaxf(s_m[0], s_m[1]), fmaxf(s_m[2], s_m[3]));
        float S = 0.f;
        #pragma unroll
        for (int w = 0; w < 4; ++w) S += s_s[w] * expf(s_m[w] - M);  // 0*exp(-inf)=0
        ws[WS_PM + blockIdx.x] = M;
        ws[WS_PS + blockIdx.x] = S;
    }
}

// ============ kE: every block reduces partials -> (M, LSE), applies its logits stripe ============
__global__ __launch_bounds__(256)
void kE(float* __restrict__ logits, const float* __restrict__ ws)
{
    __shared__ float s_m[4], s_s[4], s_off[1];
    const int tid = threadIdx.x;
    const int wv = tid >> 6, lane = tid & 63;
    const float* pm = ws + WS_PM;
    const float* ps = ws + WS_PS;

    float m = -INFINITY, s = 0.f;
    for (int i = tid; i < NPART; i += 256) {
        float mi = pm[i], si = ps[i];
        if (mi > m) { s = s * expf(m - mi) + si; m = mi; }
        else        { s += si * expf(mi - m); }
    }
    #pragma unroll
    for (int off = 32; off; off >>= 1) {
        float m2 = __shfl_xor(m, off), s2 = __shfl_xor(s, off);
        float M = fmaxf(m, m2);
        s = s * expf(m - M) + s2 * expf(m2 - M);
        m = M;
    }
    if (lane == 0) { s_m[wv] = m; s_s[wv] = s; }
    __syncthreads();
    if (tid == 0) {
        float M = fmaxf(fmaxf(s_m[0], s_m[1]), fmaxf(s_m[2], s_m[3]));
        float S = 0.f;
        #pragma unroll
        for (int w = 0; w < 4; ++w) S += s_s[w] * expf(s_m[w] - M);
        s_off[0] = M + logf(S);
    }
    __syncthreads();
    const float off = s_off[0];
    for (int v = blockIdx.x * 256 + tid; v < V; v += 128 * 256)
        logits[v] -= off;
}

extern "C" void kernel_launch(void* const* d_in, const int* in_sizes, int n_in,
                              void* d_out, int out_size, void* d_ws, size_t ws_size,
                              hipStream_t stream)
{
    const int*   tok      = (const int*)d_in[0];     // int64, read low word
    const float* hidden   = (const float*)d_in[1];   // [1,1,H]
    // d_in[2] = encoder_output: unused by reference
    const float* enc_outs = (const float*)d_in[3];   // [ML,H]
    const float* emb      = (const float*)d_in[4];   // [V,H]
    const float* W_attn   = (const float*)d_in[5];   // [ML,2H]
    const float* b_attn   = (const float*)d_in[6];
    const float* W_comb   = (const float*)d_in[7];   // [H,2H]
    const float* b_comb   = (const float*)d_in[8];
    const float* W_ih     = (const float*)d_in[9];   // [3H,H]
    const float* W_hh     = (const float*)d_in[10];  // [3H,H]
    const float* b_ih     = (const float*)d_in[11];
    const float* b_hh     = (const float*)d_in[12];
    const float* W_out    = (const float*)d_in[13];  // [V,H]
    const float* b_out    = (const float*)d_in[14];

    float* out    = (float*)d_out;
    float* ws     = (float*)d_ws;
    float* logits = out;            // [0, V)
    float* h_out  = out + V;        // [V, V+H)
    float* attnw  = out + V + H;    // [V+H, V+H+ML)

    kA<<<1 + (3 * H) / 16, 1024, 0, stream>>>(tok, hidden, enc_outs, emb,
                                              W_attn, b_attn, W_hh, b_hh, ws, attnw);
    kB<<<H / 4,             256, 0, stream>>>(W_comb, b_comb, ws);
    kC<<<H / 4,             256, 0, stream>>>(W_ih, b_ih, hidden, ws, h_out);
    kD<<<NBD,               256, 0, stream>>>(W_out, b_out, h_out, logits, ws);
    kE<<<128,               256, 0, stream>>>(logits, ws);
}